// Round 8
// baseline (171.203 us; speedup 1.0000x reference)
//
#include <hip/hip_runtime.h>
#include <math.h>

#define B_ 64
#define C_ 8
#define T_ 2048
#define K_ 64
#define NF_ 32
#define FFT_DIM_ 512
#define MLP_ 32
#define HID_ 64
#define W_ 1985
#define CH_ 32
#define NCHUNK_ 63   /* ceil(1985/32) */
#define PI_F 3.14159265358979323846f

typedef _Float16 f16x8 __attribute__((ext_vector_type(8)));
typedef _Float16 f16x2 __attribute__((ext_vector_type(2)));
typedef float    f32x4 __attribute__((ext_vector_type(4)));

// ws layout (floats): [0..1] stats | [64..4095] partial (4032) |
//                     [4096..6143] twHi (4096 halves) | [6144..8191] twLo
#define WS_PARTIAL 64
#define WS_TWHI    4096
#define WS_TWLO    6144

// ---------------- fast inline transcendentals (branchless) ----------------
__device__ __forceinline__ float fast_rcp(float x) { return __builtin_amdgcn_rcpf(x); }

// atan2(y,x)/pi, max err ~1e-6.
__device__ __forceinline__ float fast_atan2pi(float y, float x)
{
    const float ax = fabsf(x), ay = fabsf(y);
    const float mx = fmaxf(ax, ay), mn = fminf(ax, ay);
    const float r  = mn * fast_rcp(fmaxf(mx, 1e-30f));
    const float t  = r * r;
    float a = -0.003730950f;
    a = fmaf(a, t,  0.016759940f);
    a = fmaf(a, t, -0.037059946f);
    a = fmaf(a, t,  0.061602941f);
    a = fmaf(a, t, -0.105877528f);
    a = fmaf(a, t,  0.318302656f);
    a *= r;
    a = (ay > ax) ? (0.5f - a) : a;
    a = (x < 0.0f) ? (1.0f - a) : a;
    return copysignf(a, y);
}

__device__ __forceinline__ float fast_tanh(float x)
{
    const float e = __expf(2.0f * x);
    return 1.0f - 2.0f * fast_rcp(e + 1.0f);
}

__device__ __forceinline__ float fast_snake(float h, float rcp_aa, float aa)
{
    const float s = __sinf(aa * h);
    return h + s * s * rcp_aa;
}

__device__ __forceinline__ float dot4(float4 a, float4 b, float acc)
{
    return fmaf(a.x, b.x, fmaf(a.y, b.y, fmaf(a.z, b.z, fmaf(a.w, b.w, acc))));
}

// async global->LDS, 16B per lane (lane-stride-16 dest, proven r6 pattern)
__device__ __forceinline__ void gload_lds16(const void* g, void* l)
{
    __builtin_amdgcn_global_load_lds(
        (const __attribute__((address_space(1))) void*)g,
        (__attribute__((address_space(3))) void*)l, 16, 0, 0);
}

// ---------------------------------------------------------------------------
// K1: softmax stats + fp16 hi/lo twiddle table -> ws
// twiddle: row n<32: cos(2*pi*k*n/64); row n>=32: -sin(2*pi*k*(n-32)/64)
// ---------------------------------------------------------------------------
__global__ __launch_bounds__(1024) void k_pre(
    const float* __restrict__ agg, float* __restrict__ ws)
{
    __shared__ float red[1024];
    const int t = threadIdx.x;

    _Float16* twHi = (_Float16*)(ws + WS_TWHI);
    _Float16* twLo = (_Float16*)(ws + WS_TWLO);
    #pragma unroll
    for (int e = 0; e < 4; ++e) {
        const int id = t * 4 + e;          // 0..4095
        const int n = id >> 6, k = id & 63;
        const int f = n & 31;
        float s, c;
        sincosf(0.0981747704246810387f * (float)((k * f) & 63), &s, &c); // 2pi/64
        const float v = (n < 32) ? c : -s;
        const _Float16 h = (_Float16)v;
        twHi[id] = h;
        twLo[id] = (_Float16)(v - (float)h);
    }

    float m = -1e30f;
    for (int i = t; i < W_; i += 1024) m = fmaxf(m, agg[i]);
    red[t] = m;
    __syncthreads();
    for (int s = 512; s > 0; s >>= 1) {
        if (t < s) red[t] = fmaxf(red[t], red[t + s]);
        __syncthreads();
    }
    const float mx = red[0];
    __syncthreads();
    float sum = 0.f;
    for (int i = t; i < W_; i += 1024) sum += __expf(agg[i] - mx);
    red[t] = sum;
    __syncthreads();
    for (int s = 512; s > 0; s >>= 1) {
        if (t < s) red[t] += red[t + s];
        __syncthreads();
    }
    if (t == 0) { ws[0] = mx; ws[1] = red[0]; }
}

// ---------------------------------------------------------------------------
// K2: Hankel-build -> DFT via fp16 MFMA (3-pass) -> in-lane mag/ph ->
//     proj GEMM via fp16 MFMA (3-pass) -> scalar MLP. 1024 thr, ~155 KB LDS.
// ---------------------------------------------------------------------------
__global__ __launch_bounds__(1024) void k_main(
    const float* __restrict__ x,  const float* __restrict__ pw,
    const float* __restrict__ pb, const float* __restrict__ w0g,
    const float* __restrict__ b0g,const float* __restrict__ a0g,
    const float* __restrict__ w1g,const float* __restrict__ b1g,
    const float* __restrict__ a1g,const float* __restrict__ wog,
    const float* __restrict__ bog,const float* __restrict__ agg,
    const float* __restrict__ wsp, float* __restrict__ partial)
{
    // region1: Hankel hi|lo [256][64]  ->  features Ahi|Alo [32][512]
    //          -> pacc/h0L/h1L (float overlays)
    // region2: twiddle hi|lo [64][64]  ->  pw Bhi|Blo [32][512]
    __shared__ __align__(16) _Float16 reg1[32768];     // 65536 B
    __shared__ __align__(16) _Float16 reg2[32768];     // 65536 B
    __shared__ __align__(16) float w0L[64 * 36];       // 9216 B
    __shared__ __align__(16) float w1L[32 * 68];       // 8704 B
    __shared__ __align__(16) float projL[32 * 36];     // 4608 B
    __shared__ __align__(16) float xtile[C_][100];     // 3200 B
    __shared__ float smalls[260];
    __shared__ float chunkAcc[CH_];

    _Float16* HhiL  = reg1;             // [256][64] halves, granule-XOR by m
    _Float16* HloL  = reg1 + 16384;
    _Float16* AhiL  = reg1;             // [32][512] halves, granule-XOR by w
    _Float16* AloL  = reg1 + 16384;
    _Float16* twHiL = reg2;             // [64][64] halves, granule-XOR by n
    _Float16* twLoL = reg2 + 4096;
    _Float16* BhiL  = reg2;             // [32][512] halves, granule-XOR by o
    _Float16* BloL  = reg2 + 16384;
    float* pacc = (float*)reg1;         // [4][32][33] = 4224 floats
    float* h0L  = (float*)reg1;         // [32][68]
    float* h1L  = (float*)reg1 + 2176;  // [32][36]

    const int t     = threadIdx.x;
    const int chunk = blockIdx.x;
    const int b     = blockIdx.y;
    const int w0c   = chunk * CH_;
    const int wid   = t >> 6;
    const int lane  = t & 63;
    const int m16   = lane & 15;
    const int kl    = lane >> 4;

    // ---- issue twiddle -> LDS (async, pre-swizzled source) ----
    {
        const int gl = (wid & 7) * 64 + lane;      // granule 0..511
        const int n  = gl >> 3, q = gl & 7;
        const int srcg = n * 8 + (q ^ (n & 7));
        const float* srcbase = wsp + ((wid < 8) ? WS_TWHI : WS_TWLO);
        _Float16* dst = ((wid < 8) ? twHiL : twLoL) + gl * 8;
        gload_lds16((const char*)srcbase + srcg * 16, dst);
    }

    // ---- stage x tile, small weights ----
    if (t < C_ * 96) {
        const int c = t / 96;
        const int j = t - c * 96;
        int gi = w0c + j; if (gi > T_ - 1) gi = T_ - 1;
        xtile[c][j] = x[((size_t)b * C_ + c) * T_ + gi];
    }
    if (t < 257) {
        float smv;
        if      (t <  32) smv = pb[t];
        else if (t <  96) smv = b0g[t - 32];
        else if (t < 160) smv = a0g[t - 96];
        else if (t < 192) smv = b1g[t - 160];
        else if (t < 224) smv = a1g[t - 192];
        else if (t < 256) smv = wog[t - 224];
        else              smv = bog[0];
        smalls[t] = smv;
    }
    if (t < 512) {
        const float4 w0r = ((const float4*)w0g)[t];
        const int o0 = t >> 3, k40 = t & 7;
        *(float4*)&w0L[o0 * 36 + k40 * 4] = w0r;
    } else {
        const int u = t - 512;
        const float4 w1r = ((const float4*)w1g)[u];
        const int o1 = u >> 4, k41 = u & 15;
        *(float4*)&w1L[o1 * 68 + k41 * 4] = w1r;
    }
    __syncthreads();   // xtile ready; twiddle drained (barrier implies vmcnt(0))

    // ---- Hankel build: A[m=c*32+w][k] = x[w+k], fp16 hi/lo, 2 granules/thr --
    {
        #pragma unroll
        for (int s2 = 0; s2 < 2; ++s2) {
            const int id = t * 2 + s2;        // 0..2047
            const int m = id >> 3, kq = id & 7;
            const int c = m >> 5, w = m & 31;
            const float* xs = &xtile[c][w + kq * 8];
            f16x8 hi, lo;
            #pragma unroll
            for (int j = 0; j < 8; ++j) {
                const float v = xs[j];
                const _Float16 h = (_Float16)v;
                hi[j] = h;
                lo[j] = (_Float16)(v - (float)h);
            }
            const int g = m * 8 + (kq ^ (m & 7));
            *(f16x8*)&HhiL[g * 8] = hi;
            *(f16x8*)&HloL[g * 8] = lo;
        }
    }
    __syncthreads();

    // ---- DFT-MFMA: wave = m-tile (c = wid>>1, whalf = wid&1). 24 MFMA/wave --
    f32x4 dacc0 = {0.f,0.f,0.f,0.f}, dacc1 = {0.f,0.f,0.f,0.f};
    f32x4 dacc2 = {0.f,0.f,0.f,0.f}, dacc3 = {0.f,0.f,0.f,0.f};
    {
        const int arow = wid * 16 + m16;
        #pragma unroll
        for (int kstep = 0; kstep < 2; ++kstep) {
            const int kq = kstep * 4 + kl;
            const int gA = (arow * 8 + (kq ^ (arow & 7))) * 8;
            const f16x8 ah = *(const f16x8*)&HhiL[gA];
            const f16x8 al = *(const f16x8*)&HloL[gA];
            f32x4* dp[4] = { &dacc0, &dacc1, &dacc2, &dacc3 };
            #pragma unroll
            for (int nt = 0; nt < 4; ++nt) {
                const int nrow = nt * 16 + m16;
                const int gB = (nrow * 8 + (kq ^ (nrow & 7))) * 8;
                const f16x8 bh = *(const f16x8*)&twHiL[gB];
                const f16x8 bl = *(const f16x8*)&twLoL[gB];
                f32x4 a = *dp[nt];
                a = __builtin_amdgcn_mfma_f32_16x16x32_f16(ah, bh, a, 0, 0, 0);
                a = __builtin_amdgcn_mfma_f32_16x16x32_f16(al, bh, a, 0, 0, 0);
                a = __builtin_amdgcn_mfma_f32_16x16x32_f16(ah, bl, a, 0, 0, 0);
                *dp[nt] = a;
            }
        }
    }
    __syncthreads();   // Hankel + twiddle reads complete; regions reusable

    // ---- issue pw loads early (16 floats/thread, 16 VGPR) ----
    float4 pwv[4];
    {
        const int o  = t >> 5;
        const int kb = (t & 31) * 16;
        const float4* p4 = (const float4*)(pw + (size_t)o * 512 + kb);
        #pragma unroll
        for (int r = 0; r < 4; ++r) pwv[r] = p4[r];
    }

    // ---- mag/ph from dacc (8 pairs/lane) -> feature LDS (overlays Hankel) --
    {
        const int c     = wid >> 1;
        const int wbase = (wid & 1) * 16 + kl * 4;
        const float reA[2][4] = {{dacc0[0],dacc0[1],dacc0[2],dacc0[3]},
                                 {dacc1[0],dacc1[1],dacc1[2],dacc1[3]}};
        const float imA[2][4] = {{dacc2[0],dacc2[1],dacc2[2],dacc2[3]},
                                 {dacc3[0],dacc3[1],dacc3[2],dacc3[3]}};
        #pragma unroll
        for (int fi = 0; fi < 2; ++fi) {
            const int f  = fi * 16 + m16;
            const int gk = c * 8 + (f >> 2);
            #pragma unroll
            for (int r = 0; r < 4; ++r) {
                const int w  = wbase + r;
                const float re = reA[fi][r];
                const float im = imA[fi][r];
                const float mag = __logf(1.0f + __builtin_amdgcn_sqrtf(re*re + im*im));
                const float ph  = fast_atan2pi(im, re);
                const _Float16 mh = (_Float16)mag, qh = (_Float16)ph;
                f16x2 vh; vh[0] = mh; vh[1] = qh;
                f16x2 vl;
                vl[0] = (_Float16)(mag - (float)mh);
                vl[1] = (_Float16)(ph  - (float)qh);
                const int off = w * 512 + ((gk ^ (w & 7)) * 8) + 2 * (f & 3);
                *(f16x2*)&AhiL[off] = vh;
                *(f16x2*)&AloL[off] = vl;
            }
        }
    }

    // ---- convert pw regs -> Bhi/Blo fp16 (overlays twiddle) ----
    {
        const int o  = t >> 5;
        const int kb = t & 31;
        #pragma unroll
        for (int gb = 0; gb < 2; ++gb) {
            const float4 va = pwv[2 * gb];
            const float4 vb = pwv[2 * gb + 1];
            const float vv[8] = { va.x, va.y, va.z, va.w, vb.x, vb.y, vb.z, vb.w };
            f16x8 hi, lo;
            #pragma unroll
            for (int e = 0; e < 8; ++e) {
                const _Float16 h = (_Float16)vv[e];
                hi[e] = h;
                lo[e] = (_Float16)(vv[e] - (float)h);
            }
            const int gg = (kb * 2 + gb) ^ (o & 7);
            *(f16x8*)&BhiL[o * 512 + gg * 8] = hi;
            *(f16x8*)&BloL[o * 512 + gg * 8] = lo;
        }
    }
    __syncthreads();

    // ---- proj GEMM via fp16 MFMA, 3-pass (round-7 verbatim) ----
    {
        const int wt = (wid >> 1) & 1;
        const int ot = wid & 1;
        const int kq = wid >> 2;
        const int arow = wt * 16 + m16;
        const int brow = ot * 16 + m16;
        f32x4 acc = {0.f, 0.f, 0.f, 0.f};
        #pragma unroll
        for (int j = 0; j < 4; ++j) {
            const int ks = kq * 4 + j;
            const int ga = ((ks * 4 + kl) ^ (arow & 7)) * 8;
            const int gb = ((ks * 4 + kl) ^ (brow & 7)) * 8;
            const f16x8 ah = *(const f16x8*)&AhiL[arow * 512 + ga];
            const f16x8 al = *(const f16x8*)&AloL[arow * 512 + ga];
            const f16x8 bh = *(const f16x8*)&BhiL[brow * 512 + gb];
            const f16x8 bl = *(const f16x8*)&BloL[brow * 512 + gb];
            acc = __builtin_amdgcn_mfma_f32_16x16x32_f16(ah, bh, acc, 0, 0, 0);
            acc = __builtin_amdgcn_mfma_f32_16x16x32_f16(al, bh, acc, 0, 0, 0);
            acc = __builtin_amdgcn_mfma_f32_16x16x32_f16(ah, bl, acc, 0, 0, 0);
        }
        __syncthreads();   // all A/B LDS reads done before pacc overlays reg1
        #pragma unroll
        for (int r = 0; r < 4; ++r) {
            const int w = wt * 16 + kl * 4 + r;
            const int o = ot * 16 + m16;
            pacc[kq * 1056 + w * 33 + o] = acc[r];
        }
    }
    __syncthreads();

    // ---- finalize proj: reduce 4 K-quarters, bias, tanh ----
    {
        const int o = t & 31;
        const int w = t >> 5;
        float s = smalls[o];
        #pragma unroll
        for (int q = 0; q < 4; ++q) s += pacc[q * 1056 + w * 33 + o];
        projL[w * 36 + o] = fast_tanh(s) * PI_F;
    }
    __syncthreads();

    // ---- h0 = snake(proj @ w0^T + b0): thread = (w, outputs o, o+32) ----
    {
        const int w = t >> 5;
        const int o = t & 31;
        float4 pr[8];
        #pragma unroll
        for (int q = 0; q < 8; ++q) pr[q] = *(const float4*)&projL[w * 36 + q * 4];
        #pragma unroll
        for (int k = 0; k < 2; ++k) {
            const int oo = o + 32 * k;
            float acc = 0.f;
            #pragma unroll
            for (int q = 0; q < 8; ++q)
                acc = dot4(pr[q], *(const float4*)&w0L[oo * 36 + q * 4], acc);
            const float hv = acc + smalls[32 + oo];
            const float aa = fabsf(smalls[96 + oo]) + 1e-8f;
            h0L[w * 68 + oo] = fast_snake(hv, fast_rcp(aa), aa);
        }
    }
    __syncthreads();

    // ---- h1 = snake(h0 @ w1^T + b1): thread = (w, 1 output) ----
    {
        const int w = t >> 5;
        const int o = t & 31;
        float acc = 0.f;
        #pragma unroll 4
        for (int q = 0; q < 16; ++q)
            acc = dot4(*(const float4*)&h0L[w * 68 + q * 4],
                       *(const float4*)&w1L[o * 68 + q * 4], acc);
        const float hv = acc + smalls[160 + o];
        const float aa = fabsf(smalls[192 + o]) + 1e-8f;
        h1L[w * 36 + o] = fast_snake(hv, fast_rcp(aa), aa);
    }
    __syncthreads();

    // ---- out_t + softmax weight ----
    if (t < CH_) {
        const int w = t;
        float acc = 0.f;
        #pragma unroll
        for (int q = 0; q < 8; ++q)
            acc = dot4(*(const float4*)&h1L[w * 36 + q * 4],
                       *(const float4*)&smalls[224 + q * 4], acc);
        const float val = acc + smalls[256];
        const int wg = w0c + w;
        const float sw = (wg < W_) ? __expf(agg[wg] - wsp[0]) / wsp[1] : 0.f;
        chunkAcc[w] = val * sw;
    }
    __syncthreads();

    // ---- reduce 32 chunk values -> 1 partial ----
    if (t < 32) {
        float vs = chunkAcc[t];
        vs += __shfl_down(vs, 16);
        vs += __shfl_down(vs, 8);
        vs += __shfl_down(vs, 4);
        vs += __shfl_down(vs, 2);
        vs += __shfl_down(vs, 1);
        if (t == 0) partial[(size_t)chunk * B_ + b] = vs;
    }
}

// ---------------------------------------------------------------------------
// K3: final reduce over chunks -> d_out[b]
// ---------------------------------------------------------------------------
__global__ void k_reduce(const float* __restrict__ partial, float* __restrict__ out)
{
    const int b = threadIdx.x;
    if (b < B_) {
        float s = 0.f;
        for (int c = 0; c < NCHUNK_; ++c) s += partial[(size_t)c * B_ + b];
        out[b] = s;
    }
}

// ---------------------------------------------------------------------------
extern "C" void kernel_launch(void* const* d_in, const int* in_sizes, int n_in,
                              void* d_out, int out_size, void* d_ws, size_t ws_size,
                              hipStream_t stream)
{
    const float* x   = (const float*)d_in[0];
    const float* pw  = (const float*)d_in[1];
    const float* pb  = (const float*)d_in[2];
    const float* w0  = (const float*)d_in[3];
    const float* b0  = (const float*)d_in[4];
    const float* a0  = (const float*)d_in[5];
    const float* w1  = (const float*)d_in[6];
    const float* b1  = (const float*)d_in[7];
    const float* a1  = (const float*)d_in[8];
    const float* wo  = (const float*)d_in[9];
    const float* bo  = (const float*)d_in[10];
    const float* agg = (const float*)d_in[11];
    float* ws  = (float*)d_ws;
    float* out = (float*)d_out;

    k_pre<<<1, 1024, 0, stream>>>(agg, ws);
    dim3 grid(NCHUNK_, B_);
    k_main<<<grid, 1024, 0, stream>>>(x, pw, pb, w0, b0, a0, w1, b1, a1, wo, bo,
                                      agg, ws, ws + WS_PARTIAL);
    k_reduce<<<1, 64, 0, stream>>>(ws + WS_PARTIAL, out);
}

// Round 9
// 132.616 us; speedup vs baseline: 1.2910x; 1.2910x over previous
//
#include <hip/hip_runtime.h>
#include <math.h>

#define B_ 64
#define C_ 8
#define T_ 2048
#define NF_ 32
#define MLP_ 32
#define HID_ 64
#define W_ 1985
#define CH_ 32
#define NCHUNK_ 63   /* ceil(1985/32) */
#define PI_F 3.14159265358979323846f

typedef _Float16 f16x8 __attribute__((ext_vector_type(8)));
typedef _Float16 f16x2 __attribute__((ext_vector_type(2)));
typedef float    f32x4 __attribute__((ext_vector_type(4)));

// ws layout (floats): [0..1] stats | [64..4095] partial (4032) |
// [4096..6143] twHi (4096 f16) | [6144..8191] twLo | [8192..24575] pw packed u32
#define WS_PARTIAL 64
#define WS_TWHI    4096
#define WS_TWLO    6144
#define WS_PWPK    8192

// ---------------- fast inline transcendentals (branchless) ----------------
__device__ __forceinline__ float fast_rcp(float x) { return __builtin_amdgcn_rcpf(x); }

__device__ __forceinline__ float fast_atan2pi(float y, float x)
{
    const float ax = fabsf(x), ay = fabsf(y);
    const float mx = fmaxf(ax, ay), mn = fminf(ax, ay);
    const float r  = mn * fast_rcp(fmaxf(mx, 1e-30f));
    const float t  = r * r;
    float a = -0.003730950f;
    a = fmaf(a, t,  0.016759940f);
    a = fmaf(a, t, -0.037059946f);
    a = fmaf(a, t,  0.061602941f);
    a = fmaf(a, t, -0.105877528f);
    a = fmaf(a, t,  0.318302656f);
    a *= r;
    a = (ay > ax) ? (0.5f - a) : a;
    a = (x < 0.0f) ? (1.0f - a) : a;
    return copysignf(a, y);
}

__device__ __forceinline__ float fast_tanh(float x)
{
    const float e = __expf(2.0f * x);
    return 1.0f - 2.0f * fast_rcp(e + 1.0f);
}

__device__ __forceinline__ float fast_snake(float h, float rcp_aa, float aa)
{
    const float s = __sinf(aa * h);
    return h + s * s * rcp_aa;
}

__device__ __forceinline__ float dot4(float4 a, float4 b, float acc)
{
    return fmaf(a.x, b.x, fmaf(a.y, b.y, fmaf(a.z, b.z, fmaf(a.w, b.w, acc))));
}

// pack f32 -> (f16 hi, f16 lo) in one u32 (hi in low 16 bits)
__device__ __forceinline__ unsigned packhl(float v)
{
    const _Float16 h = (_Float16)v;
    const _Float16 l = (_Float16)(v - (float)h);
    f16x2 p; p[0] = h; p[1] = l;
    return __builtin_bit_cast(unsigned, p);
}

// from 8 packed u32 (ascending k) build hi-f16x8 and lo-f16x8 via v_perm
__device__ __forceinline__ void unpack8(const unsigned* u, f16x8& ah, f16x8& al)
{
    union { unsigned w[4]; f16x8 v; } H, L;
    #pragma unroll
    for (int j = 0; j < 4; ++j) {
        H.w[j] = __builtin_amdgcn_perm(u[2*j+1], u[2*j], 0x05040100u);
        L.w[j] = __builtin_amdgcn_perm(u[2*j+1], u[2*j], 0x07060302u);
    }
    ah = H.v; al = L.v;
}

// async global->LDS, 16B per lane (lane-stride-16 dest, proven r6-r8 pattern)
__device__ __forceinline__ void gload_lds16(const void* g, void* l)
{
    __builtin_amdgcn_global_load_lds(
        (const __attribute__((address_space(1))) void*)g,
        (__attribute__((address_space(3))) void*)l, 16, 0, 0);
}

// ---------------------------------------------------------------------------
// K1: softmax stats + twiddle tables (f16 hi/lo) + packed pw -> ws
// ---------------------------------------------------------------------------
__global__ __launch_bounds__(1024) void k_pre(
    const float* __restrict__ agg, const float* __restrict__ pw,
    float* __restrict__ ws)
{
    __shared__ float red[1024];
    const int t = threadIdx.x;

    _Float16* twHi = (_Float16*)(ws + WS_TWHI);
    _Float16* twLo = (_Float16*)(ws + WS_TWLO);
    #pragma unroll
    for (int e = 0; e < 4; ++e) {
        const int id = t * 4 + e;          // 0..4095
        const int n = id >> 6, k = id & 63;
        const int f = n & 31;
        float s, c;
        sincosf(0.0981747704246810387f * (float)((k * f) & 63), &s, &c); // 2pi/64
        const float v = (n < 32) ? c : -s;
        const _Float16 h = (_Float16)v;
        twHi[id] = h;
        twLo[id] = (_Float16)(v - (float)h);
    }

    unsigned* pwpk = (unsigned*)(ws + WS_PWPK);
    #pragma unroll
    for (int e = 0; e < 16; ++e) {
        const int id = e * 1024 + t;       // 0..16383
        pwpk[id] = packhl(pw[id]);
    }

    float m = -1e30f;
    for (int i = t; i < W_; i += 1024) m = fmaxf(m, agg[i]);
    red[t] = m;
    __syncthreads();
    for (int s = 512; s > 0; s >>= 1) {
        if (t < s) red[t] = fmaxf(red[t], red[t + s]);
        __syncthreads();
    }
    const float mx = red[0];
    __syncthreads();
    float sum = 0.f;
    for (int i = t; i < W_; i += 1024) sum += __expf(agg[i] - mx);
    red[t] = sum;
    __syncthreads();
    for (int s = 512; s > 0; s >>= 1) {
        if (t < s) red[t] += red[t + s];
        __syncthreads();
    }
    if (t == 0) { ws[0] = mx; ws[1] = red[0]; }
}

// ---------------------------------------------------------------------------
// K2: DFT-MFMA (A from packed xtile, B twiddle LDS) -> in-lane mag/ph (packed)
//     -> K-split-2 proj GEMM (A packed featH LDS, B packed pw from global)
//     -> scalar MLP.  1024 thr, ~76 KB LDS -> 2 blocks/CU (32 waves).
// ---------------------------------------------------------------------------
__global__ __launch_bounds__(1024, 8) void k_main(
    const float* __restrict__ x,  const float* __restrict__ pw,
    const float* __restrict__ pb, const float* __restrict__ w0g,
    const float* __restrict__ b0g,const float* __restrict__ a0g,
    const float* __restrict__ w1g,const float* __restrict__ b1g,
    const float* __restrict__ a1g,const float* __restrict__ wog,
    const float* __restrict__ bog,const float* __restrict__ agg,
    const float* __restrict__ wsp, float* __restrict__ partial)
{
    __shared__ __align__(16) _Float16 twHiL[64 * 64];   // 8192 B
    __shared__ __align__(16) _Float16 twLoL[64 * 64];   // 8192 B
    __shared__ __align__(16) unsigned featH[32 * 256];  // 32768 B (K-half, packed)
    __shared__ __align__(16) unsigned xtileP[C_][100];  // 3200 B (packed)
    __shared__ __align__(16) float w0L[64 * 36];        // 9216 B
    __shared__ __align__(16) float w1L[32 * 68];        // 8704 B
    __shared__ __align__(16) float projL[32 * 36];      // 4608 B
    __shared__ float smalls[260];
    __shared__ float chunkAcc[CH_];
    // total ~76 KB -> 2 blocks/CU

    float* pacc = (float*)featH;            // [4][32][33] = 4224 f (overlay)
    float* h0L  = (float*)featH;            // [32][68]
    float* h1L  = (float*)featH + 2176;     // [32][36]

    const int t     = threadIdx.x;
    const int chunk = blockIdx.x;
    const int b     = blockIdx.y;
    const int w0c   = chunk * CH_;
    const int wid   = t >> 6;
    const int lane  = t & 63;
    const int m16   = lane & 15;
    const int kl    = lane >> 4;
    const int cdft  = wid >> 1;             // DFT channel 0..7

    // ---- async twiddle -> LDS (pre-swizzled source, r8 pattern) ----
    {
        const int gl = (wid & 7) * 64 + lane;      // granule 0..511
        const int n  = gl >> 3, q = gl & 7;
        const int srcg = n * 8 + (q ^ (n & 7));
        const float* srcbase = wsp + ((wid < 8) ? WS_TWHI : WS_TWLO);
        _Float16* dst = ((wid < 8) ? twHiL : twLoL) + gl * 8;
        gload_lds16((const char*)srcbase + srcg * 16, dst);
    }

    // ---- stage x tile (packed), smalls, w0L, w1L ----
    if (t < C_ * 96) {
        const int c = t / 96;
        const int j = t - c * 96;
        int gi = w0c + j; if (gi > T_ - 1) gi = T_ - 1;
        xtileP[c][j] = packhl(x[((size_t)b * C_ + c) * T_ + gi]);
    }
    if (t < 257) {
        float smv;
        if      (t <  32) smv = pb[t];
        else if (t <  96) smv = b0g[t - 32];
        else if (t < 160) smv = a0g[t - 96];
        else if (t < 192) smv = b1g[t - 160];
        else if (t < 224) smv = a1g[t - 192];
        else if (t < 256) smv = wog[t - 224];
        else              smv = bog[0];
        smalls[t] = smv;
    }
    if (t < 512) {
        const float4 w0r = ((const float4*)w0g)[t];
        const int o0 = t >> 3, k40 = t & 7;
        *(float4*)&w0L[o0 * 36 + k40 * 4] = w0r;
    } else {
        const int u = t - 512;
        const float4 w1r = ((const float4*)w1g)[u];
        const int o1 = u >> 4, k41 = u & 15;
        *(float4*)&w1L[o1 * 68 + k41 * 4] = w1r;
    }
    __syncthreads();   // xtile/weights ready; twiddle drained (barrier=vmcnt0)

    // ---- DFT-MFMA: A built in-reg from xtileP, B from twiddle LDS ----
    f32x4 dacc0 = {0.f,0.f,0.f,0.f}, dacc1 = {0.f,0.f,0.f,0.f};
    f32x4 dacc2 = {0.f,0.f,0.f,0.f}, dacc3 = {0.f,0.f,0.f,0.f};
    const int wra = (wid & 1) * 16 + m16;   // A-row's window index w
    {
        #pragma unroll
        for (int kstep = 0; kstep < 2; ++kstep) {
            const int kq = kstep * 4 + kl;
            unsigned ut[8];
            #pragma unroll
            for (int j = 0; j < 8; ++j) ut[j] = xtileP[cdft][wra + kq * 8 + j];
            f16x8 ah, al; unpack8(ut, ah, al);
            f32x4* dp[4] = { &dacc0, &dacc1, &dacc2, &dacc3 };
            #pragma unroll
            for (int nt = 0; nt < 4; ++nt) {
                const int nrow = nt * 16 + m16;
                const int gB = (nrow * 8 + (kq ^ (nrow & 7))) * 8;
                const f16x8 bh = *(const f16x8*)&twHiL[gB];
                const f16x8 bl = *(const f16x8*)&twLoL[gB];
                f32x4 a = *dp[nt];
                a = __builtin_amdgcn_mfma_f32_16x16x32_f16(ah, bh, a, 0, 0, 0);
                a = __builtin_amdgcn_mfma_f32_16x16x32_f16(al, bh, a, 0, 0, 0);
                a = __builtin_amdgcn_mfma_f32_16x16x32_f16(ah, bl, a, 0, 0, 0);
                *dp[nt] = a;
            }
        }
    }
    // no barrier needed: mag/ph consumes dacc in-lane

    // ---- mag/ph (all waves); waves 0-7 write featH (c 0..3), 8-15 hold ----
    unsigned heldM[2][4], heldP[2][4];
    {
        const int wbase = (wid & 1) * 16 + kl * 4;
        const int ccl   = cdft & 3;
        const float reA[2][4] = {{dacc0[0],dacc0[1],dacc0[2],dacc0[3]},
                                 {dacc1[0],dacc1[1],dacc1[2],dacc1[3]}};
        const float imA[2][4] = {{dacc2[0],dacc2[1],dacc2[2],dacc2[3]},
                                 {dacc3[0],dacc3[1],dacc3[2],dacc3[3]}};
        #pragma unroll
        for (int fi = 0; fi < 2; ++fi) {
            const int f = fi * 16 + m16;
            #pragma unroll
            for (int r = 0; r < 4; ++r) {
                const int w  = wbase + r;
                const float re = reA[fi][r], im = imA[fi][r];
                const float mag = __logf(1.0f + __builtin_amdgcn_sqrtf(re*re + im*im));
                const float ph  = fast_atan2pi(im, re);
                const unsigned um = packhl(mag), up = packhl(ph);
                if (wid < 8) {
                    const int g  = ccl * 16 + fi * 8 + (m16 >> 1);
                    const int gs = g ^ (w & 7);
                    *(uint2*)&featH[w * 256 + gs * 4 + 2 * (f & 1)] =
                        make_uint2(um, up);
                } else {
                    heldM[fi][r] = um; heldP[fi][r] = up;
                }
            }
        }
    }
    __syncthreads();

    // ---- proj GEMM: K-split 2, A from featH (packed), B from global pwpk ----
    const unsigned* pwpk = (const unsigned*)(wsp + WS_PWPK);
    {
        const int wt = (wid >> 1) & 1;
        const int ot = wid & 1;
        const int kq4 = wid >> 2;
        const int arow = wt * 16 + m16;
        const int brow = ot * 16 + m16;
        f32x4 acc = {0.f, 0.f, 0.f, 0.f};
        #pragma unroll
        for (int p = 0; p < 2; ++p) {
            #pragma unroll
            for (int kstep = 0; kstep < 2; ++kstep) {
                const int kp = kq4 * 64 + kstep * 32 + kl * 8;   // local k'
                // B: 8 packed u32 straight from global (L2-hot)
                const unsigned* bp = pwpk + (size_t)brow * 512 + p * 256 + kp;
                unsigned ub[8];
                *(uint4*)&ub[0] = *(const uint4*)bp;
                *(uint4*)&ub[4] = *(const uint4*)(bp + 4);
                f16x8 bh, bl; unpack8(ub, bh, bl);
                // A: 2 swizzled granules from featH
                const int g0 = kp >> 2;
                unsigned ua[8];
                *(uint4*)&ua[0] = *(const uint4*)&featH[arow * 256 + ((g0    ) ^ (arow & 7)) * 4];
                *(uint4*)&ua[4] = *(const uint4*)&featH[arow * 256 + ((g0 + 1) ^ (arow & 7)) * 4];
                f16x8 ah, al; unpack8(ua, ah, al);
                acc = __builtin_amdgcn_mfma_f32_16x16x32_f16(ah, bh, acc, 0, 0, 0);
                acc = __builtin_amdgcn_mfma_f32_16x16x32_f16(al, bh, acc, 0, 0, 0);
                acc = __builtin_amdgcn_mfma_f32_16x16x32_f16(ah, bl, acc, 0, 0, 0);
            }
            if (p == 0) {
                __syncthreads();      // pass-0 featH reads done
                if (wid >= 8) {       // waves 8-15: write c 4..7 features
                    const int wbase = (wid & 1) * 16 + kl * 4;
                    const int ccl   = cdft & 3;
                    #pragma unroll
                    for (int fi = 0; fi < 2; ++fi) {
                        const int f = fi * 16 + m16;
                        #pragma unroll
                        for (int r = 0; r < 4; ++r) {
                            const int w  = wbase + r;
                            const int g  = ccl * 16 + fi * 8 + (m16 >> 1);
                            const int gs = g ^ (w & 7);
                            *(uint2*)&featH[w * 256 + gs * 4 + 2 * (f & 1)] =
                                make_uint2(heldM[fi][r], heldP[fi][r]);
                        }
                    }
                }
                __syncthreads();
            }
        }
        __syncthreads();   // pass-1 featH reads done; region free for pacc
        #pragma unroll
        for (int r = 0; r < 4; ++r) {
            const int w = wt * 16 + kl * 4 + r;
            const int o = ot * 16 + m16;
            pacc[kq4 * 1056 + w * 33 + o] = acc[r];
        }
    }
    __syncthreads();

    // ---- finalize proj: reduce 4 kq partials, bias, tanh ----
    {
        const int o = t & 31;
        const int w = t >> 5;
        float s = smalls[o];
        #pragma unroll
        for (int q = 0; q < 4; ++q) s += pacc[q * 1056 + w * 33 + o];
        projL[w * 36 + o] = fast_tanh(s) * PI_F;
    }
    __syncthreads();

    // ---- h0 = snake(proj @ w0^T + b0): thread = (w, outputs o, o+32) ----
    {
        const int w = t >> 5;
        const int o = t & 31;
        float4 pr[8];
        #pragma unroll
        for (int q = 0; q < 8; ++q) pr[q] = *(const float4*)&projL[w * 36 + q * 4];
        #pragma unroll
        for (int k = 0; k < 2; ++k) {
            const int oo = o + 32 * k;
            float acc = 0.f;
            #pragma unroll
            for (int q = 0; q < 8; ++q)
                acc = dot4(pr[q], *(const float4*)&w0L[oo * 36 + q * 4], acc);
            const float hv = acc + smalls[32 + oo];
            const float aa = fabsf(smalls[96 + oo]) + 1e-8f;
            h0L[w * 68 + oo] = fast_snake(hv, fast_rcp(aa), aa);
        }
    }
    __syncthreads();

    // ---- h1 = snake(h0 @ w1^T + b1): thread = (w, 1 output) ----
    {
        const int w = t >> 5;
        const int o = t & 31;
        float acc = 0.f;
        #pragma unroll 4
        for (int q = 0; q < 16; ++q)
            acc = dot4(*(const float4*)&h0L[w * 68 + q * 4],
                       *(const float4*)&w1L[o * 68 + q * 4], acc);
        const float hv = acc + smalls[160 + o];
        const float aa = fabsf(smalls[192 + o]) + 1e-8f;
        h1L[w * 36 + o] = fast_snake(hv, fast_rcp(aa), aa);
    }
    __syncthreads();

    // ---- out_t + softmax weight ----
    if (t < CH_) {
        const int w = t;
        float acc = 0.f;
        #pragma unroll
        for (int q = 0; q < 8; ++q)
            acc = dot4(*(const float4*)&h1L[w * 36 + q * 4],
                       *(const float4*)&smalls[224 + q * 4], acc);
        const float val = acc + smalls[256];
        const int wg = w0c + w;
        const float sw = (wg < W_) ? __expf(agg[wg] - wsp[0]) / wsp[1] : 0.f;
        chunkAcc[w] = val * sw;
    }
    __syncthreads();

    // ---- reduce 32 chunk values -> 1 partial ----
    if (t < 32) {
        float vs = chunkAcc[t];
        vs += __shfl_down(vs, 16);
        vs += __shfl_down(vs, 8);
        vs += __shfl_down(vs, 4);
        vs += __shfl_down(vs, 2);
        vs += __shfl_down(vs, 1);
        if (t == 0) partial[(size_t)chunk * B_ + b] = vs;
    }
}

// ---------------------------------------------------------------------------
// K3: final reduce over chunks -> d_out[b]
// ---------------------------------------------------------------------------
__global__ void k_reduce(const float* __restrict__ partial, float* __restrict__ out)
{
    const int b = threadIdx.x;
    if (b < B_) {
        float s = 0.f;
        for (int c = 0; c < NCHUNK_; ++c) s += partial[(size_t)c * B_ + b];
        out[b] = s;
    }
}

// ---------------------------------------------------------------------------
extern "C" void kernel_launch(void* const* d_in, const int* in_sizes, int n_in,
                              void* d_out, int out_size, void* d_ws, size_t ws_size,
                              hipStream_t stream)
{
    const float* x   = (const float*)d_in[0];
    const float* pw  = (const float*)d_in[1];
    const float* pb  = (const float*)d_in[2];
    const float* w0  = (const float*)d_in[3];
    const float* b0  = (const float*)d_in[4];
    const float* a0  = (const float*)d_in[5];
    const float* w1  = (const float*)d_in[6];
    const float* b1  = (const float*)d_in[7];
    const float* a1  = (const float*)d_in[8];
    const float* wo  = (const float*)d_in[9];
    const float* bo  = (const float*)d_in[10];
    const float* agg = (const float*)d_in[11];
    float* ws  = (float*)d_ws;
    float* out = (float*)d_out;

    k_pre<<<1, 1024, 0, stream>>>(agg, pw, ws);
    dim3 grid(NCHUNK_, B_);
    k_main<<<grid, 1024, 0, stream>>>(x, pw, pb, w0, b0, a0, w1, b1, a1, wo, bo,
                                      agg, ws, ws + WS_PARTIAL);
    k_reduce<<<1, 64, 0, stream>>>(ws + WS_PARTIAL, out);
}

// Round 10
// 122.574 us; speedup vs baseline: 1.3967x; 1.0819x over previous
//
#include <hip/hip_runtime.h>
#include <math.h>

#define B_ 64
#define C_ 8
#define T_ 2048
#define NF_ 32
#define MLP_ 32
#define HID_ 64
#define W_ 1985
#define CH_ 32
#define NCHUNK_ 63   /* ceil(1985/32) */
#define PI_F 3.14159265358979323846f

typedef _Float16 f16x8 __attribute__((ext_vector_type(8)));
typedef _Float16 f16x2 __attribute__((ext_vector_type(2)));
typedef float    f32x4 __attribute__((ext_vector_type(4)));

// ws layout (floats):
// [0..1] stats | [64..4095] partial | [4096..6143] twHi | [6144..8191] twLo |
// [8192..16383] pwHi (16384 f16) | [16384..24575] pwLo |
// [24576..25599] w0Hi | [25600..26623] w0Lo | [26624..27647] w1Hi | [27648..28671] w1Lo
#define WS_PARTIAL 64
#define WS_TWHI    4096
#define WS_TWLO    6144
#define WS_PWHI    8192
#define WS_PWLO    16384
#define WS_W0HI    24576
#define WS_W0LO    25600
#define WS_W1HI    26624
#define WS_W1LO    27648

// ---------------- fast inline transcendentals (branchless) ----------------
__device__ __forceinline__ float fast_rcp(float x) { return __builtin_amdgcn_rcpf(x); }

__device__ __forceinline__ float fast_atan2pi(float y, float x)
{
    const float ax = fabsf(x), ay = fabsf(y);
    const float mx = fmaxf(ax, ay), mn = fminf(ax, ay);
    const float r  = mn * fast_rcp(fmaxf(mx, 1e-30f));
    const float t  = r * r;
    float a = -0.003730950f;
    a = fmaf(a, t,  0.016759940f);
    a = fmaf(a, t, -0.037059946f);
    a = fmaf(a, t,  0.061602941f);
    a = fmaf(a, t, -0.105877528f);
    a = fmaf(a, t,  0.318302656f);
    a *= r;
    a = (ay > ax) ? (0.5f - a) : a;
    a = (x < 0.0f) ? (1.0f - a) : a;
    return copysignf(a, y);
}

__device__ __forceinline__ float fast_tanh(float x)
{
    const float e = __expf(2.0f * x);
    return 1.0f - 2.0f * fast_rcp(e + 1.0f);
}

__device__ __forceinline__ float fast_snake(float h, float rcp_aa, float aa)
{
    const float s = __sinf(aa * h);
    return h + s * s * rcp_aa;
}

__device__ __forceinline__ float dot4(float4 a, float4 b, float acc)
{
    return fmaf(a.x, b.x, fmaf(a.y, b.y, fmaf(a.z, b.z, fmaf(a.w, b.w, acc))));
}

// pack f32 -> (f16 hi, f16 lo) in one u32 (hi in low 16 bits)
__device__ __forceinline__ unsigned packhl(float v)
{
    const _Float16 h = (_Float16)v;
    const _Float16 l = (_Float16)(v - (float)h);
    f16x2 p; p[0] = h; p[1] = l;
    return __builtin_bit_cast(unsigned, p);
}

// from 8 packed u32 (ascending k) build hi-f16x8 and lo-f16x8 via v_perm
__device__ __forceinline__ void unpack8(const unsigned* u, f16x8& ah, f16x8& al)
{
    union { unsigned w[4]; f16x8 v; } H, L;
    #pragma unroll
    for (int j = 0; j < 4; ++j) {
        H.w[j] = __builtin_amdgcn_perm(u[2*j+1], u[2*j], 0x05040100u);
        L.w[j] = __builtin_amdgcn_perm(u[2*j+1], u[2*j], 0x07060302u);
    }
    ah = H.v; al = L.v;
}

// async global->LDS, 16B per lane (lane-stride-16 dest, proven r6-r9 pattern)
__device__ __forceinline__ void gload_lds16(const void* g, void* l)
{
    __builtin_amdgcn_global_load_lds(
        (const __attribute__((address_space(1))) void*)g,
        (__attribute__((address_space(3))) void*)l, 16, 0, 0);
}

// ---------------------------------------------------------------------------
// K1: softmax stats + twiddle (f16 hi/lo) + pw/w0/w1 hi-lo planes -> ws
// ---------------------------------------------------------------------------
__global__ __launch_bounds__(1024) void k_pre(
    const float* __restrict__ agg, const float* __restrict__ pw,
    const float* __restrict__ w0g, const float* __restrict__ w1g,
    float* __restrict__ ws)
{
    __shared__ float red[1024];
    const int t = threadIdx.x;

    _Float16* twHi = (_Float16*)(ws + WS_TWHI);
    _Float16* twLo = (_Float16*)(ws + WS_TWLO);
    #pragma unroll
    for (int e = 0; e < 4; ++e) {
        const int id = t * 4 + e;          // 0..4095
        const int n = id >> 6, k = id & 63;
        const int f = n & 31;
        float s, c;
        sincosf(0.0981747704246810387f * (float)((k * f) & 63), &s, &c); // 2pi/64
        const float v = (n < 32) ? c : -s;
        const _Float16 h = (_Float16)v;
        twHi[id] = h;
        twLo[id] = (_Float16)(v - (float)h);
    }

    _Float16* pwHi = (_Float16*)(ws + WS_PWHI);
    _Float16* pwLo = (_Float16*)(ws + WS_PWLO);
    #pragma unroll
    for (int e = 0; e < 16; ++e) {
        const int id = e * 1024 + t;       // 0..16383
        const float v = pw[id];
        const _Float16 h = (_Float16)v;
        pwHi[id] = h;
        pwLo[id] = (_Float16)(v - (float)h);
    }

    _Float16* w0Hi = (_Float16*)(ws + WS_W0HI);
    _Float16* w0Lo = (_Float16*)(ws + WS_W0LO);
    _Float16* w1Hi = (_Float16*)(ws + WS_W1HI);
    _Float16* w1Lo = (_Float16*)(ws + WS_W1LO);
    #pragma unroll
    for (int e = 0; e < 2; ++e) {
        const int id = e * 1024 + t;       // 0..2047
        const float v0 = w0g[id];
        const _Float16 h0 = (_Float16)v0;
        w0Hi[id] = h0;
        w0Lo[id] = (_Float16)(v0 - (float)h0);
        const float v1 = w1g[id];
        const _Float16 h1 = (_Float16)v1;
        w1Hi[id] = h1;
        w1Lo[id] = (_Float16)(v1 - (float)h1);
    }

    float m = -1e30f;
    for (int i = t; i < W_; i += 1024) m = fmaxf(m, agg[i]);
    red[t] = m;
    __syncthreads();
    for (int s = 512; s > 0; s >>= 1) {
        if (t < s) red[t] = fmaxf(red[t], red[t + s]);
        __syncthreads();
    }
    const float mx = red[0];
    __syncthreads();
    float sum = 0.f;
    for (int i = t; i < W_; i += 1024) sum += __expf(agg[i] - mx);
    red[t] = sum;
    __syncthreads();
    for (int s = 512; s > 0; s >>= 1) {
        if (t < s) red[t] += red[t + s];
        __syncthreads();
    }
    if (t == 0) { ws[0] = mx; ws[1] = red[0]; }
}

// ---------------------------------------------------------------------------
// K2: DFT-MFMA -> mag/ph -> proj GEMM (plane operands, no perms) ->
//     MFMA h0/h1 -> out. 1024 thr, ~67 KB LDS -> 2 blocks/CU.
// ---------------------------------------------------------------------------
__global__ __launch_bounds__(1024, 8) void k_main(
    const float* __restrict__ x,  const float* __restrict__ pw,
    const float* __restrict__ pb, const float* __restrict__ w0g,
    const float* __restrict__ b0g,const float* __restrict__ a0g,
    const float* __restrict__ w1g,const float* __restrict__ b1g,
    const float* __restrict__ a1g,const float* __restrict__ wog,
    const float* __restrict__ bog,const float* __restrict__ agg,
    const float* __restrict__ wsp, float* __restrict__ partial)
{
    __shared__ __align__(16) _Float16 twHiL[4096];     // 8192 B
    __shared__ __align__(16) _Float16 twLoL[4096];     // 8192 B
    __shared__ __align__(16) _Float16 featP[16384];    // 32768 B: hi[32][256], lo
    __shared__ __align__(16) _Float16 projP[2560];     // 5120 B: hi[32][40], lo
    __shared__ __align__(16) _Float16 h0P[4608];       // 9216 B: hi[32][72], lo
    __shared__ __align__(16) unsigned xtileP[C_][100]; // 3200 B (packed hi|lo)
    __shared__ float smalls[260];
    __shared__ float chunkAcc[CH_];
    // total ~67 KB -> 2 blocks/CU

    _Float16* featHi = featP;               // [32][256]
    _Float16* featLo = featP + 8192;
    _Float16* projHi = projP;               // [32][40] (pad 40)
    _Float16* projLo = projP + 1280;
    _Float16* h0Hi   = h0P;                 // [32][72] (pad 72)
    _Float16* h0Lo   = h0P + 2304;
    float* pacc = (float*)featP;            // [4][32][33] = 4224 f (overlay)
    float* h1L  = (float*)featP;            // [32][36] (after pacc dead)

    const int t     = threadIdx.x;
    const int chunk = blockIdx.x;
    const int b     = blockIdx.y;
    const int w0c   = chunk * CH_;
    const int wid   = t >> 6;
    const int lane  = t & 63;
    const int m16   = lane & 15;
    const int kl    = lane >> 4;
    const int cdft  = wid >> 1;             // DFT channel 0..7

    // ---- async twiddle -> LDS (pre-swizzled source, r8/r9 pattern) ----
    {
        const int gl = (wid & 7) * 64 + lane;      // granule 0..511
        const int n  = gl >> 3, q = gl & 7;
        const int srcg = n * 8 + (q ^ (n & 7));
        const float* srcbase = wsp + ((wid < 8) ? WS_TWHI : WS_TWLO);
        _Float16* dst = ((wid < 8) ? twHiL : twLoL) + gl * 8;
        gload_lds16((const char*)srcbase + srcg * 16, dst);
    }

    // ---- stage x tile (packed), smalls ----
    if (t < C_ * 96) {
        const int c = t / 96;
        const int j = t - c * 96;
        int gi = w0c + j; if (gi > T_ - 1) gi = T_ - 1;
        xtileP[c][j] = packhl(x[((size_t)b * C_ + c) * T_ + gi]);
    }
    if (t < 257) {
        float smv;
        if      (t <  32) smv = pb[t];
        else if (t <  96) smv = b0g[t - 32];
        else if (t < 160) smv = a0g[t - 96];
        else if (t < 192) smv = b1g[t - 160];
        else if (t < 224) smv = a1g[t - 192];
        else if (t < 256) smv = wog[t - 224];
        else              smv = bog[0];
        smalls[t] = smv;
    }
    __syncthreads();   // xtile/smalls ready; twiddle drained (barrier=vmcnt0)

    // ---- DFT-MFMA: A built in-reg from xtileP (perm), B twiddle planes ----
    f32x4 dacc0 = {0.f,0.f,0.f,0.f}, dacc1 = {0.f,0.f,0.f,0.f};
    f32x4 dacc2 = {0.f,0.f,0.f,0.f}, dacc3 = {0.f,0.f,0.f,0.f};
    const int wra = (wid & 1) * 16 + m16;   // A-row's window index w
    {
        #pragma unroll
        for (int kstep = 0; kstep < 2; ++kstep) {
            const int kq = kstep * 4 + kl;
            unsigned ut[8];
            #pragma unroll
            for (int j = 0; j < 8; ++j) ut[j] = xtileP[cdft][wra + kq * 8 + j];
            f16x8 ah, al; unpack8(ut, ah, al);
            f32x4* dp[4] = { &dacc0, &dacc1, &dacc2, &dacc3 };
            #pragma unroll
            for (int nt = 0; nt < 4; ++nt) {
                const int nrow = nt * 16 + m16;
                const int gB = (nrow * 8 + (kq ^ (nrow & 7))) * 8;
                const f16x8 bh = *(const f16x8*)&twHiL[gB];
                const f16x8 bl = *(const f16x8*)&twLoL[gB];
                f32x4 a = *dp[nt];
                a = __builtin_amdgcn_mfma_f32_16x16x32_f16(ah, bh, a, 0, 0, 0);
                a = __builtin_amdgcn_mfma_f32_16x16x32_f16(al, bh, a, 0, 0, 0);
                a = __builtin_amdgcn_mfma_f32_16x16x32_f16(ah, bl, a, 0, 0, 0);
                *dp[nt] = a;
            }
        }
    }

    // ---- mag/ph (all waves); waves 0-7 write feat planes (c0-3), 8-15 hold --
    unsigned heldHi[2][4], heldLo[2][4];
    {
        const int wbase = (wid & 1) * 16 + kl * 4;
        const int ccl   = cdft & 3;
        const float reA[2][4] = {{dacc0[0],dacc0[1],dacc0[2],dacc0[3]},
                                 {dacc1[0],dacc1[1],dacc1[2],dacc1[3]}};
        const float imA[2][4] = {{dacc2[0],dacc2[1],dacc2[2],dacc2[3]},
                                 {dacc3[0],dacc3[1],dacc3[2],dacc3[3]}};
        #pragma unroll
        for (int fi = 0; fi < 2; ++fi) {
            const int f = fi * 16 + m16;
            const int g = ccl * 8 + (f >> 2);
            const int sub = 2 * (f & 3);
            #pragma unroll
            for (int r = 0; r < 4; ++r) {
                const int w  = wbase + r;
                const float re = reA[fi][r], im = imA[fi][r];
                const float mag = __logf(1.0f + __builtin_amdgcn_sqrtf(re*re + im*im));
                const float ph  = fast_atan2pi(im, re);
                const _Float16 mh = (_Float16)mag;
                const _Float16 qh = (_Float16)ph;
                f16x2 vh; vh[0] = mh; vh[1] = qh;
                f16x2 vl;
                vl[0] = (_Float16)(mag - (float)mh);
                vl[1] = (_Float16)(ph  - (float)qh);
                if (wid < 8) {
                    const int off = w * 256 + ((g ^ (w & 7)) * 8) + sub;
                    *(f16x2*)&featHi[off] = vh;
                    *(f16x2*)&featLo[off] = vl;
                } else {
                    heldHi[fi][r] = __builtin_bit_cast(unsigned, vh);
                    heldLo[fi][r] = __builtin_bit_cast(unsigned, vl);
                }
            }
        }
    }
    __syncthreads();

    // ---- proj GEMM: K-split 2, plane operands (no perms) ----
    const _Float16* pwHi = (const _Float16*)(wsp + WS_PWHI);
    const _Float16* pwLo = (const _Float16*)(wsp + WS_PWLO);
    {
        const int wt = (wid >> 1) & 1;
        const int ot = wid & 1;
        const int kq4 = wid >> 2;
        const int arow = wt * 16 + m16;
        const int brow = ot * 16 + m16;
        f32x4 acc = {0.f, 0.f, 0.f, 0.f};
        #pragma unroll
        for (int p = 0; p < 2; ++p) {
            #pragma unroll
            for (int kstep = 0; kstep < 2; ++kstep) {
                const int kp = kq4 * 64 + kstep * 32 + kl * 8;   // local k'
                const f16x8 bh = *(const f16x8*)&pwHi[(size_t)brow * 512 + p * 256 + kp];
                const f16x8 bl = *(const f16x8*)&pwLo[(size_t)brow * 512 + p * 256 + kp];
                const int g0 = kp >> 3;
                const int offA = arow * 256 + ((g0 ^ (arow & 7)) * 8);
                const f16x8 ah = *(const f16x8*)&featHi[offA];
                const f16x8 al = *(const f16x8*)&featLo[offA];
                acc = __builtin_amdgcn_mfma_f32_16x16x32_f16(ah, bh, acc, 0, 0, 0);
                acc = __builtin_amdgcn_mfma_f32_16x16x32_f16(al, bh, acc, 0, 0, 0);
                acc = __builtin_amdgcn_mfma_f32_16x16x32_f16(ah, bl, acc, 0, 0, 0);
            }
            if (p == 0) {
                __syncthreads();      // pass-0 feat reads done
                if (wid >= 8) {       // waves 8-15: write c4-7 features
                    const int wbase = (wid & 1) * 16 + kl * 4;
                    const int ccl   = cdft & 3;
                    #pragma unroll
                    for (int fi = 0; fi < 2; ++fi) {
                        const int f = fi * 16 + m16;
                        const int g = ccl * 8 + (f >> 2);
                        const int sub = 2 * (f & 3);
                        #pragma unroll
                        for (int r = 0; r < 4; ++r) {
                            const int w  = wbase + r;
                            const int off = w * 256 + ((g ^ (w & 7)) * 8) + sub;
                            *(unsigned*)&featHi[off] = heldHi[fi][r];
                            *(unsigned*)&featLo[off] = heldLo[fi][r];
                        }
                    }
                }
                __syncthreads();
            }
        }
        __syncthreads();   // pass-1 feat reads done; region free for pacc
        #pragma unroll
        for (int r = 0; r < 4; ++r) {
            const int w = wt * 16 + kl * 4 + r;
            const int o = ot * 16 + m16;
            pacc[kq4 * 1056 + w * 33 + o] = acc[r];
        }
    }
    __syncthreads();

    // ---- finalize proj: reduce 4 kq partials, bias, tanh -> projP planes ----
    {
        const int o = t & 31;
        const int w = t >> 5;
        float s = smalls[o];
        #pragma unroll
        for (int q = 0; q < 4; ++q) s += pacc[q * 1056 + w * 33 + o];
        const float pr = fast_tanh(s) * PI_F;
        const _Float16 h = (_Float16)pr;
        projHi[w * 40 + o] = h;
        projLo[w * 40 + o] = (_Float16)(pr - (float)h);
    }
    __syncthreads();

    // ---- h0 = snake(proj @ w0^T + b0) via MFMA: 8 waves, 3 MFMA each ----
    const _Float16* w0Hi = (const _Float16*)(wsp + WS_W0HI);
    const _Float16* w0Lo = (const _Float16*)(wsp + WS_W0LO);
    if (wid < 8) {
        const int wt = wid & 1;
        const int ot = wid >> 1;          // 0..3
        const int arow = wt * 16 + m16;   // proj row w
        const int brow = ot * 16 + m16;   // h0 output o
        const f16x8 ah = *(const f16x8*)&projHi[arow * 40 + kl * 8];
        const f16x8 al = *(const f16x8*)&projLo[arow * 40 + kl * 8];
        const f16x8 bh = *(const f16x8*)&w0Hi[brow * 32 + kl * 8];
        const f16x8 bl = *(const f16x8*)&w0Lo[brow * 32 + kl * 8];
        f32x4 acc = {0.f, 0.f, 0.f, 0.f};
        acc = __builtin_amdgcn_mfma_f32_16x16x32_f16(ah, bh, acc, 0, 0, 0);
        acc = __builtin_amdgcn_mfma_f32_16x16x32_f16(al, bh, acc, 0, 0, 0);
        acc = __builtin_amdgcn_mfma_f32_16x16x32_f16(ah, bl, acc, 0, 0, 0);
        const int o  = ot * 16 + m16;
        const float b0v = smalls[32 + o];
        const float aa  = fabsf(smalls[96 + o]) + 1e-8f;
        const float ra  = fast_rcp(aa);
        #pragma unroll
        for (int r = 0; r < 4; ++r) {
            const int w = wt * 16 + kl * 4 + r;
            const float hv = fast_snake(acc[r] + b0v, ra, aa);
            const _Float16 h = (_Float16)hv;
            h0Hi[w * 72 + o] = h;
            h0Lo[w * 72 + o] = (_Float16)(hv - (float)h);
        }
    }
    __syncthreads();

    // ---- h1 = snake(h0 @ w1^T + b1) via MFMA: 4 waves, 6 MFMA each ----
    const _Float16* w1Hi = (const _Float16*)(wsp + WS_W1HI);
    const _Float16* w1Lo = (const _Float16*)(wsp + WS_W1LO);
    if (wid < 4) {
        const int wt = wid & 1;
        const int ot = wid >> 1;          // 0..1
        const int arow = wt * 16 + m16;   // h0 row w
        const int brow = ot * 16 + m16;   // h1 output o
        f32x4 acc = {0.f, 0.f, 0.f, 0.f};
        #pragma unroll
        for (int ks = 0; ks < 2; ++ks) {
            const f16x8 ah = *(const f16x8*)&h0Hi[arow * 72 + ks * 32 + kl * 8];
            const f16x8 al = *(const f16x8*)&h0Lo[arow * 72 + ks * 32 + kl * 8];
            const f16x8 bh = *(const f16x8*)&w1Hi[brow * 64 + ks * 32 + kl * 8];
            const f16x8 bl = *(const f16x8*)&w1Lo[brow * 64 + ks * 32 + kl * 8];
            acc = __builtin_amdgcn_mfma_f32_16x16x32_f16(ah, bh, acc, 0, 0, 0);
            acc = __builtin_amdgcn_mfma_f32_16x16x32_f16(al, bh, acc, 0, 0, 0);
            acc = __builtin_amdgcn_mfma_f32_16x16x32_f16(ah, bl, acc, 0, 0, 0);
        }
        const int o  = ot * 16 + m16;
        const float b1v = smalls[160 + o];
        const float aa  = fabsf(smalls[192 + o]) + 1e-8f;
        const float ra  = fast_rcp(aa);
        #pragma unroll
        for (int r = 0; r < 4; ++r) {
            const int w = wt * 16 + kl * 4 + r;
            h1L[w * 36 + o] = fast_snake(acc[r] + b1v, ra, aa);
        }
    }
    __syncthreads();

    // ---- out_t + softmax weight ----
    if (t < CH_) {
        const int w = t;
        float acc = 0.f;
        #pragma unroll
        for (int q = 0; q < 8; ++q)
            acc = dot4(*(const float4*)&h1L[w * 36 + q * 4],
                       *(const float4*)&smalls[224 + q * 4], acc);
        const float val = acc + smalls[256];
        const int wg = w0c + w;
        const float sw = (wg < W_) ? __expf(agg[wg] - wsp[0]) / wsp[1] : 0.f;
        chunkAcc[w] = val * sw;
    }
    __syncthreads();

    // ---- reduce 32 chunk values -> 1 partial ----
    if (t < 32) {
        float vs = chunkAcc[t];
        vs += __shfl_down(vs, 16);
        vs += __shfl_down(vs, 8);
        vs += __shfl_down(vs, 4);
        vs += __shfl_down(vs, 2);
        vs += __shfl_down(vs, 1);
        if (t == 0) partial[(size_t)chunk * B_ + b] = vs;
    }
}

// ---------------------------------------------------------------------------
// K3: final reduce over chunks -> d_out[b]
// ---------------------------------------------------------------------------
__global__ void k_reduce(const float* __restrict__ partial, float* __restrict__ out)
{
    const int b = threadIdx.x;
    if (b < B_) {
        float s = 0.f;
        for (int c = 0; c < NCHUNK_; ++c) s += partial[(size_t)c * B_ + b];
        out[b] = s;
    }
}

// ---------------------------------------------------------------------------
extern "C" void kernel_launch(void* const* d_in, const int* in_sizes, int n_in,
                              void* d_out, int out_size, void* d_ws, size_t ws_size,
                              hipStream_t stream)
{
    const float* x   = (const float*)d_in[0];
    const float* pw  = (const float*)d_in[1];
    const float* pb  = (const float*)d_in[2];
    const float* w0  = (const float*)d_in[3];
    const float* b0  = (const float*)d_in[4];
    const float* a0  = (const float*)d_in[5];
    const float* w1  = (const float*)d_in[6];
    const float* b1  = (const float*)d_in[7];
    const float* a1  = (const float*)d_in[8];
    const float* wo  = (const float*)d_in[9];
    const float* bo  = (const float*)d_in[10];
    const float* agg = (const float*)d_in[11];
    float* ws  = (float*)d_ws;
    float* out = (float*)d_out;

    k_pre<<<1, 1024, 0, stream>>>(agg, pw, w0, w1, ws);
    dim3 grid(NCHUNK_, B_);
    k_main<<<grid, 1024, 0, stream>>>(x, pw, pb, w0, b0, a0, w1, b1, a1, wo, bo,
                                      agg, ws, ws + WS_PARTIAL);
    k_reduce<<<1, 64, 0, stream>>>(ws + WS_PARTIAL, out);
}